// Round 1
// baseline (1188.191 us; speedup 1.0000x reference)
//
#include <hip/hip_runtime.h>

typedef unsigned short u16;
typedef short s16x8 __attribute__((ext_vector_type(8)));
typedef float f32x4 __attribute__((ext_vector_type(4)));
typedef u16   u16x4 __attribute__((ext_vector_type(4)));

#define GLDS16(g, l) __builtin_amdgcn_global_load_lds( \
    (const __attribute__((address_space(1))) void*)(g), \
    (__attribute__((address_space(3))) void*)(l), 16, 0, 0)

__device__ __forceinline__ void split1(float x, u16& h, u16& l) {
  __bf16 hb = (__bf16)x;                 // RNE truncate to bf16 (hi)
  __bf16 lb = (__bf16)(x - (float)hb);   // residual (lo)
  h = __builtin_bit_cast(u16, hb);
  l = __builtin_bit_cast(u16, lb);
}

// ---------------------------------------------------------------------------
// Histogram + Shannon-entropy gate. One block per row (5120 f32).
// Matches torch.histc semantics via the reference's formula exactly.
// ---------------------------------------------------------------------------
__global__ __launch_bounds__(256) void k_hist(const float* __restrict__ E,
                                              float* __restrict__ flags) {
  __shared__ unsigned int hist[100];
  const int tid = threadIdx.x;
  const int row = blockIdx.x;
  if (tid < 100) hist[tid] = 0u;
  __syncthreads();
  const float4* rp = (const float4*)(E + (size_t)row * 5120);
#pragma unroll
  for (int j = 0; j < 5; ++j) {
    float4 v = rp[j * 256 + tid];
    float xs[4] = {v.x, v.y, v.z, v.w};
#pragma unroll
    for (int c = 0; c < 4; ++c) {
      float x = xs[c];
      float t = (x + 5.0f) / 0.1f;       // (x - LO) / width, width=0.1f
      int b = (int)floorf(t);
      b = b < 0 ? 0 : (b > 99 ? 99 : b);
      if (x >= -5.0f && x <= 5.0f) atomicAdd(&hist[b], 1u);
    }
  }
  __syncthreads();
  if (tid == 0) {
    float S = 0.f;
    for (int i = 0; i < 100; ++i) S += (float)hist[i];
    float d = S + 1e-9f;
    float h = 0.f;
    for (int i = 0; i < 100; ++i) {
      float p = (float)hist[i] / d;
      h -= p * logf(p + 1e-9f);
    }
    flags[row] = (h >= 2.5f) ? 1.0f : 0.0f;
  }
}

// ---------------------------------------------------------------------------
// f32 -> (bf16 hi, bf16 lo) bulk converter (for sensing_matrix, [N,K] layout)
// ---------------------------------------------------------------------------
__global__ void k_convert(const float* __restrict__ X, u16* __restrict__ Xh,
                          u16* __restrict__ Xl, int n4) {
  int idx = blockIdx.x * 256 + threadIdx.x;
  if (idx < n4) {
    float4 v = ((const float4*)X)[idx];
    u16 h0, h1, h2, h3, l0, l1, l2, l3;
    split1(v.x, h0, l0); split1(v.y, h1, l1);
    split1(v.z, h2, l2); split1(v.w, h3, l3);
    ((u16x4*)Xh)[idx] = u16x4{h0, h1, h2, h3};
    ((u16x4*)Xl)[idx] = u16x4{l0, l1, l2, l3};
  }
}

// adjacency prep: adjT hi/lo (for GEMM2 B), M = adj*adj (f32), MT hi/lo (P-chain B)
__global__ void k_prep_adj(const float* __restrict__ adj, u16* __restrict__ aTh,
                           u16* __restrict__ aTl, float* __restrict__ Mf,
                           u16* __restrict__ Mth, u16* __restrict__ Mtl) {
  int idx = blockIdx.x * 256 + threadIdx.x;
  if (idx >= 512 * 512) return;
  int i = idx >> 9, j = idx & 511;
  float a = adj[idx];
  float m = a * a;
  Mf[idx] = m;
  u16 h, l;
  split1(a, h, l); aTh[j * 512 + i] = h; aTl[j * 512 + i] = l;
  split1(m, h, l); Mth[j * 512 + i] = h; Mtl[j * 512 + i] = l;
}

__global__ void k_prep_w1t(const float* __restrict__ w1, float* __restrict__ w1T) {
  int idx = blockIdx.x * 256 + threadIdx.x;
  if (idx < 512 * 128) { int n = idx >> 7, h = idx & 127; w1T[h * 512 + n] = w1[idx]; }
}

// ---------------------------------------------------------------------------
// Split-bf16 GEMM (fp32-accurate): C[M,N] = A[M,K] @ B^T where B given as
// [N,K] hi/lo bf16. A is f32, reg-staged + split on the fly into LDS.
// 3-product: Ah*Bh + Ah*Bl + Al*Bh on mfma_f32_16x16x32_bf16.
// BM=BN=128, BK=64, 256 thr (4 waves, 2x2 of 64x64). XOR swizzle (row&7)<<3
// on LDS k-index, applied on A ds_write, B pre-swizzled global src, and reads.
// Optional per-row scale 'flags' in epilogue (entropy filter).
// ---------------------------------------------------------------------------
__global__ __launch_bounds__(256, 2) void gemm_sbf16(
    const float* __restrict__ A, const u16* __restrict__ Bh,
    const u16* __restrict__ Bl, float* __restrict__ C,
    const float* __restrict__ flags, int N, int K) {
  __shared__ u16 lAh[128 * 64], lAl[128 * 64], lBh[128 * 64], lBl[128 * 64];
  const int tid = threadIdx.x;
  const int lane = tid & 63;
  const int w = tid >> 6;
  const int wm = (w >> 1) * 64, wn = (w & 1) * 64;
  const int row0 = blockIdx.y * 128;
  const int col0 = blockIdx.x * 128;

  f32x4 acc[4][4] = {};

  const int rr = lane & 15;
  const int kgrp = (lane >> 4) * 8;
  const int sw = (rr & 7) << 3;            // read-side swizzle (elem units)
  const int bsrc = (((lane & 7) ^ (lane >> 3)) << 3);  // B pre-swizzled src col
  const int brow = lane >> 3;              // row within 8-row stage group

  const int nk = K >> 6;
  for (int kt = 0; kt < nk; ++kt) {
    const int k0 = kt << 6;
    // ---- stage B tiles via async global->LDS (linear dest, swizzled source)
    {
      const int rbase = w * 32;
#pragma unroll
      for (int i = 0; i < 4; ++i) {
        const size_t gro = (size_t)(col0 + rbase + i * 8 + brow) * K + k0 + bsrc;
        GLDS16(Bh + gro, &lBh[(rbase + i * 8) * 64]);
        GLDS16(Bl + gro, &lBl[(rbase + i * 8) * 64]);
      }
    }
    // ---- stage A: load f32, split, swizzled ds_write
    float4 av[8];
#pragma unroll
    for (int j = 0; j < 8; ++j) {
      int idx = j * 256 + tid;
      int r = idx >> 4, kv = (idx & 15) * 4;
      av[j] = *(const float4*)(A + (size_t)(row0 + r) * K + k0 + kv);
    }
#pragma unroll
    for (int j = 0; j < 8; ++j) {
      int idx = j * 256 + tid;
      int r = idx >> 4, kv = (idx & 15) * 4;
      int col = kv ^ ((r & 7) << 3);
      u16 h0, h1, h2, h3, l0, l1, l2, l3;
      split1(av[j].x, h0, l0); split1(av[j].y, h1, l1);
      split1(av[j].z, h2, l2); split1(av[j].w, h3, l3);
      *(u16x4*)&lAh[r * 64 + col] = u16x4{h0, h1, h2, h3};
      *(u16x4*)&lAl[r * 64 + col] = u16x4{l0, l1, l2, l3};
    }
    __syncthreads();   // drains vmcnt (global_load_lds) + lgkmcnt (ds_write)
    // ---- compute: 2 kk steps, 16 frag-pairs x 3 MFMA each
#pragma unroll
    for (int kk = 0; kk < 2; ++kk) {
      const int kx = (kk * 32 + kgrp) ^ sw;
      s16x8 ah[4], al[4], bh[4], bl[4];
#pragma unroll
      for (int mi = 0; mi < 4; ++mi) {
        const int r = (wm + mi * 16 + rr) * 64 + kx;
        ah[mi] = *(const s16x8*)&lAh[r];
        al[mi] = *(const s16x8*)&lAl[r];
      }
#pragma unroll
      for (int ni = 0; ni < 4; ++ni) {
        const int r = (wn + ni * 16 + rr) * 64 + kx;
        bh[ni] = *(const s16x8*)&lBh[r];
        bl[ni] = *(const s16x8*)&lBl[r];
      }
#pragma unroll
      for (int mi = 0; mi < 4; ++mi)
#pragma unroll
        for (int ni = 0; ni < 4; ++ni) {
          acc[mi][ni] = __builtin_amdgcn_mfma_f32_16x16x32_bf16(ah[mi], bh[ni], acc[mi][ni], 0, 0, 0);
          acc[mi][ni] = __builtin_amdgcn_mfma_f32_16x16x32_bf16(ah[mi], bl[ni], acc[mi][ni], 0, 0, 0);
          acc[mi][ni] = __builtin_amdgcn_mfma_f32_16x16x32_bf16(al[mi], bh[ni], acc[mi][ni], 0, 0, 0);
        }
    }
    __syncthreads();
  }
  // ---- epilogue: C layout col=lane&15, row=(lane>>4)*4+j  (m89-verified)
  const int cr = (lane >> 4) * 4;
  const int cc = lane & 15;
#pragma unroll
  for (int mi = 0; mi < 4; ++mi)
#pragma unroll
    for (int j = 0; j < 4; ++j) {
      const int grow = row0 + wm + mi * 16 + cr + j;
      const float f = flags ? flags[grow] : 1.0f;
#pragma unroll
      for (int ni = 0; ni < 4; ++ni)
        C[(size_t)grow * N + col0 + wn + ni * 16 + cc] = acc[mi][ni][j] * f;
    }
}

// ---------------------------------------------------------------------------
// Traces for the expm Taylor series
// ---------------------------------------------------------------------------
__global__ void k_trace_diag(const float* __restrict__ M, const float* __restrict__ P2,
                             const float* __restrict__ P3, const float* __restrict__ P4,
                             const float* __restrict__ P5, const float* __restrict__ P6,
                             float* __restrict__ tr) {
  __shared__ float red[8];
  const float* mats[6] = {M, P2, P3, P4, P5, P6};
  const int t = threadIdx.x;  // 512
  if (t < 6) tr[6 + t] = 0.0f;  // zero the atomic slots for the dot kernels
  for (int s = 0; s < 6; ++s) {
    float v = mats[s][t * 513];  // diag element
#pragma unroll
    for (int off = 32; off; off >>= 1) v += __shfl_down(v, off);
    if ((t & 63) == 0) red[t >> 6] = v;
    __syncthreads();
    if (t == 0) {
      float a = 0.f;
      for (int i = 0; i < 8; ++i) a += red[i];
      tr[s] = a;
    }
    __syncthreads();
  }
}

__global__ void k_trace_dot(const float* __restrict__ Pa, const float* __restrict__ Pb,
                            float* __restrict__ slot) {
  int idx = blockIdx.x * 256 + threadIdx.x;
  float acc = 0.f;
  for (int t = idx; t < 512 * 512; t += 65536) {
    int i = t >> 9, j = t & 511;
    acc += Pa[t] * Pb[(j << 9) + i];
  }
#pragma unroll
  for (int off = 32; off; off >>= 1) acc += __shfl_down(acc, off);
  if ((threadIdx.x & 63) == 0) atomicAdd(slot, acc);
}

__global__ void k_finalize(const float* __restrict__ tr, float* __restrict__ outh) {
  if (threadIdx.x == 0) {
    double h = 0.0, f = 1.0;
    for (int k = 1; k <= 12; ++k) { f *= k; h += (double)tr[k - 1] / f; }
    outh[0] = (float)h;
  }
}

// ---------------------------------------------------------------------------
// Fused robust policy: Z=s@w1+b1 -> mask -> g=(mask*colsum(w2))@w1T ->
// s' = s - 0.1*sign(g) -> relu(s'@w1+b1)@w2+b2 -> softmax.  16 rows/block.
// ---------------------------------------------------------------------------
__global__ __launch_bounds__(256, 2) void k_policy(
    const float* __restrict__ state, const float* __restrict__ w1,
    const float* __restrict__ w1T, const float* __restrict__ w2,
    const float* __restrict__ b1, const float* __restrict__ b2,
    float* __restrict__ out) {
  __shared__ float s[16][513];
  __shared__ float q[16][130];
  __shared__ float Rp[16][130];
  __shared__ float lg[16][66];
  __shared__ float csum[128];
  const int tid = threadIdx.x;
  const int r0 = blockIdx.x * 16;

#pragma unroll
  for (int j = 0; j < 8; ++j) {          // load 16x512 state rows
    int idx = j * 256 + tid;
    int r = idx >> 7, c4 = (idx & 127) * 4;
    float4 v = *(const float4*)(state + (size_t)(r0 + r) * 512 + c4);
    s[r][c4 + 0] = v.x; s[r][c4 + 1] = v.y; s[r][c4 + 2] = v.z; s[r][c4 + 3] = v.w;
  }
  if (tid < 128) {                        // c_h = sum_a w2[h][a]
    float a = 0.f;
    const float4* wp = (const float4*)(w2 + tid * 64);
#pragma unroll
    for (int i = 0; i < 16; ++i) { float4 v = wp[i]; a += v.x + v.y + v.z + v.w; }
    csum[tid] = a;
  }
  __syncthreads();

  {  // step 1: Z, q   (thread: 4 h x 2 rows)
    const int h4 = (tid & 31) * 4;
    const int rg = (tid >> 5) * 2;
    float z00 = 0, z01 = 0, z02 = 0, z03 = 0, z10 = 0, z11 = 0, z12 = 0, z13 = 0;
#pragma unroll 4
    for (int n = 0; n < 512; ++n) {
      float4 wv = *(const float4*)(w1 + (size_t)n * 128 + h4);
      float s0 = s[rg][n], s1 = s[rg + 1][n];
      z00 += s0 * wv.x; z01 += s0 * wv.y; z02 += s0 * wv.z; z03 += s0 * wv.w;
      z10 += s1 * wv.x; z11 += s1 * wv.y; z12 += s1 * wv.z; z13 += s1 * wv.w;
    }
    float4 bb = *(const float4*)(b1 + h4);
    q[rg][h4 + 0] = (z00 + bb.x > 0.f) ? csum[h4 + 0] : 0.f;
    q[rg][h4 + 1] = (z01 + bb.y > 0.f) ? csum[h4 + 1] : 0.f;
    q[rg][h4 + 2] = (z02 + bb.z > 0.f) ? csum[h4 + 2] : 0.f;
    q[rg][h4 + 3] = (z03 + bb.w > 0.f) ? csum[h4 + 3] : 0.f;
    q[rg + 1][h4 + 0] = (z10 + bb.x > 0.f) ? csum[h4 + 0] : 0.f;
    q[rg + 1][h4 + 1] = (z11 + bb.y > 0.f) ? csum[h4 + 1] : 0.f;
    q[rg + 1][h4 + 2] = (z12 + bb.z > 0.f) ? csum[h4 + 2] : 0.f;
    q[rg + 1][h4 + 3] = (z13 + bb.w > 0.f) ? csum[h4 + 3] : 0.f;
  }
  __syncthreads();

  {  // step 2: g = q @ w1T, s' = s - 0.1*sign(g)   (thread: 4 n x 8 rows)
    const int n4 = (tid & 127) * 4;
    const int rg = (tid >> 7) * 8;
    float g[8][4] = {};
#pragma unroll 2
    for (int h = 0; h < 128; ++h) {
      float4 wv = *(const float4*)(w1T + (size_t)h * 512 + n4);
#pragma unroll
      for (int i = 0; i < 8; ++i) {
        float qq = q[rg + i][h];
        g[i][0] += qq * wv.x; g[i][1] += qq * wv.y;
        g[i][2] += qq * wv.z; g[i][3] += qq * wv.w;
      }
    }
#pragma unroll
    for (int i = 0; i < 8; ++i)
#pragma unroll
      for (int c = 0; c < 4; ++c) {
        float gg = g[i][c];
        float sgn = (gg > 0.f) ? 1.f : ((gg < 0.f) ? -1.f : 0.f);
        s[rg + i][n4 + c] -= 0.1f * sgn;
      }
  }
  __syncthreads();

  {  // step 3: Z' = s'@w1+b1, Rp = relu
    const int h4 = (tid & 31) * 4;
    const int rg = (tid >> 5) * 2;
    float z00 = 0, z01 = 0, z02 = 0, z03 = 0, z10 = 0, z11 = 0, z12 = 0, z13 = 0;
#pragma unroll 4
    for (int n = 0; n < 512; ++n) {
      float4 wv = *(const float4*)(w1 + (size_t)n * 128 + h4);
      float s0 = s[rg][n], s1 = s[rg + 1][n];
      z00 += s0 * wv.x; z01 += s0 * wv.y; z02 += s0 * wv.z; z03 += s0 * wv.w;
      z10 += s1 * wv.x; z11 += s1 * wv.y; z12 += s1 * wv.z; z13 += s1 * wv.w;
    }
    float4 bb = *(const float4*)(b1 + h4);
    Rp[rg][h4 + 0] = fmaxf(z00 + bb.x, 0.f);
    Rp[rg][h4 + 1] = fmaxf(z01 + bb.y, 0.f);
    Rp[rg][h4 + 2] = fmaxf(z02 + bb.z, 0.f);
    Rp[rg][h4 + 3] = fmaxf(z03 + bb.w, 0.f);
    Rp[rg + 1][h4 + 0] = fmaxf(z10 + bb.x, 0.f);
    Rp[rg + 1][h4 + 1] = fmaxf(z11 + bb.y, 0.f);
    Rp[rg + 1][h4 + 2] = fmaxf(z12 + bb.z, 0.f);
    Rp[rg + 1][h4 + 3] = fmaxf(z13 + bb.w, 0.f);
  }
  __syncthreads();

  {  // step 4: logits = Rp @ w2 + b2   (thread: 4 a x 1 row)
    const int a4 = (tid & 15) * 4;
    const int r = tid >> 4;
    float L0 = 0, L1 = 0, L2 = 0, L3 = 0;
#pragma unroll 4
    for (int h = 0; h < 128; ++h) {
      float rp = Rp[r][h];
      float4 wv = *(const float4*)(w2 + (size_t)h * 64 + a4);
      L0 += rp * wv.x; L1 += rp * wv.y; L2 += rp * wv.z; L3 += rp * wv.w;
    }
    float4 bb = *(const float4*)(b2 + a4);
    lg[r][a4 + 0] = L0 + bb.x; lg[r][a4 + 1] = L1 + bb.y;
    lg[r][a4 + 2] = L2 + bb.z; lg[r][a4 + 3] = L3 + bb.w;
  }
  __syncthreads();

  if (tid < 16) {  // softmax per row
    float mx = -3.0e38f;
    for (int a = 0; a < 64; ++a) mx = fmaxf(mx, lg[tid][a]);
    float sum = 0.f;
    for (int a = 0; a < 64; ++a) { float e = __expf(lg[tid][a] - mx); lg[tid][a] = e; sum += e; }
    float inv = 1.f / sum;
    for (int a = 0; a < 64; ++a) lg[tid][a] *= inv;
  }
  __syncthreads();
#pragma unroll
  for (int j = 0; j < 4; ++j) {
    int idx = j * 256 + tid;
    int r = idx >> 6, a = idx & 63;
    out[(size_t)(r0 + r) * 64 + a] = lg[r][a];
  }
}

// ---------------------------------------------------------------------------
extern "C" void kernel_launch(void* const* d_in, const int* in_sizes, int n_in,
                              void* d_out, int out_size, void* d_ws, size_t ws_size,
                              hipStream_t stream) {
  const float* E   = (const float*)d_in[0];   // [16384,5120]
  const float* S   = (const float*)d_in[1];   // [512,5120]
  const float* adj = (const float*)d_in[2];   // [512,512]
  const float* w1  = (const float*)d_in[3];   // [512,128]
  const float* b1  = (const float*)d_in[4];   // [128]
  const float* w2  = (const float*)d_in[5];   // [128,64]
  const float* b2  = (const float*)d_in[6];   // [64]
  float* out = (float*)d_out;                 // [16384*64] probs + [1] h_acyclic

  char* wsb = (char*)d_ws;
  size_t off = 0;
  auto alloc = [&](size_t bytes) { void* p = wsb + off; off += (bytes + 255) & ~(size_t)255; return p; };
  u16*   Sh   = (u16*)alloc((size_t)512 * 5120 * 2);
  u16*   Sl   = (u16*)alloc((size_t)512 * 5120 * 2);
  float* filt = (float*)alloc((size_t)16384 * 512 * 4);
  float* st   = (float*)alloc((size_t)16384 * 512 * 4);
  float* w1T  = (float*)alloc((size_t)128 * 512 * 4);
  float* flg  = (float*)alloc((size_t)16384 * 4);
  u16*   aTh  = (u16*)alloc((size_t)512 * 512 * 2);
  u16*   aTl  = (u16*)alloc((size_t)512 * 512 * 2);
  float* Mf   = (float*)alloc((size_t)512 * 512 * 4);
  u16*   Mth  = (u16*)alloc((size_t)512 * 512 * 2);
  u16*   Mtl  = (u16*)alloc((size_t)512 * 512 * 2);
  float* P2   = (float*)alloc((size_t)512 * 512 * 4);
  float* P3   = (float*)alloc((size_t)512 * 512 * 4);
  float* P4   = (float*)alloc((size_t)512 * 512 * 4);
  float* P5   = (float*)alloc((size_t)512 * 512 * 4);
  float* P6   = (float*)alloc((size_t)512 * 512 * 4);
  float* tr   = (float*)alloc(256);
  (void)in_sizes; (void)n_in; (void)out_size; (void)ws_size;

  k_hist<<<16384, 256, 0, stream>>>(E, flg);
  k_convert<<<2560, 256, 0, stream>>>(S, Sh, Sl, 512 * 5120 / 4);
  k_prep_adj<<<1024, 256, 0, stream>>>(adj, aTh, aTl, Mf, Mth, Mtl);
  k_prep_w1t<<<256, 256, 0, stream>>>(w1, w1T);

  dim3 gBig(4, 128);
  gemm_sbf16<<<gBig, 256, 0, stream>>>(E, Sh, Sl, filt, flg, 512, 5120);       // compressed+filter
  gemm_sbf16<<<gBig, 256, 0, stream>>>(filt, aTh, aTl, st, nullptr, 512, 512); // state

  dim3 gSm(4, 4);
  gemm_sbf16<<<gSm, 256, 0, stream>>>(Mf, Mth, Mtl, P2, nullptr, 512, 512);
  gemm_sbf16<<<gSm, 256, 0, stream>>>(P2, Mth, Mtl, P3, nullptr, 512, 512);
  gemm_sbf16<<<gSm, 256, 0, stream>>>(P3, Mth, Mtl, P4, nullptr, 512, 512);
  gemm_sbf16<<<gSm, 256, 0, stream>>>(P4, Mth, Mtl, P5, nullptr, 512, 512);
  gemm_sbf16<<<gSm, 256, 0, stream>>>(P5, Mth, Mtl, P6, nullptr, 512, 512);

  k_trace_diag<<<1, 512, 0, stream>>>(Mf, P2, P3, P4, P5, P6, tr);
  k_trace_dot<<<256, 256, 0, stream>>>(P3, P4, tr + 6);
  k_trace_dot<<<256, 256, 0, stream>>>(P4, P4, tr + 7);
  k_trace_dot<<<256, 256, 0, stream>>>(P4, P5, tr + 8);
  k_trace_dot<<<256, 256, 0, stream>>>(P5, P5, tr + 9);
  k_trace_dot<<<256, 256, 0, stream>>>(P5, P6, tr + 10);
  k_trace_dot<<<256, 256, 0, stream>>>(P6, P6, tr + 11);
  k_finalize<<<1, 64, 0, stream>>>(tr, out + (size_t)16384 * 64);

  k_policy<<<1024, 256, 0, stream>>>(st, w1, w1T, w2, b1, b2, out);
}

// Round 4
// 999.448 us; speedup vs baseline: 1.1888x; 1.1888x over previous
//
#include <hip/hip_runtime.h>

typedef unsigned short u16;
typedef short s16x8 __attribute__((ext_vector_type(8)));
typedef float f32x4 __attribute__((ext_vector_type(4)));
typedef u16   u16x4 __attribute__((ext_vector_type(4)));

#define GLDS16(g, l) __builtin_amdgcn_global_load_lds( \
    (const __attribute__((address_space(1))) void*)(g), \
    (__attribute__((address_space(3))) void*)(l), 16, 0, 0)

__device__ __forceinline__ void split1(float x, u16& h, u16& l) {
  __bf16 hb = (__bf16)x;                 // RNE to bf16 (hi)
  __bf16 lb = (__bf16)(x - (float)hb);   // residual (lo)
  h = __builtin_bit_cast(u16, hb);
  l = __builtin_bit_cast(u16, lb);
}

// ---------------------------------------------------------------------------
// Histogram + entropy gate: ONE WAVE PER ROW. 4 rows/block, per-wave LDS hist
// (no cross-wave interference), wave-parallel entropy (no serial logf tail).
// ---------------------------------------------------------------------------
__global__ __launch_bounds__(256) void k_hist(const float* __restrict__ E,
                                              float* __restrict__ flags) {
  __shared__ unsigned int H4[4][104];
  const int lane = threadIdx.x & 63;
  const int w = threadIdx.x >> 6;
  const int row = blockIdx.x * 4 + w;
  unsigned int* H = H4[w];
  for (int b = lane; b < 104; b += 64) H[b] = 0u;
  __syncthreads();
  const float4* rp = (const float4*)(E + (size_t)row * 5120);
#pragma unroll 4
  for (int j = 0; j < 20; ++j) {
    float4 v = rp[j * 64 + lane];
    float xs[4] = {v.x, v.y, v.z, v.w};
#pragma unroll
    for (int c = 0; c < 4; ++c) {
      float x = xs[c];
      float t = (x - (-5.0f)) / 0.1f;
      int b = (int)floorf(t);
      b = b < 0 ? 0 : (b > 99 ? 99 : b);
      if (x >= -5.0f && x <= 5.0f) atomicAdd(&H[b], 1u);
    }
  }
  __syncthreads();
  float c0 = (float)H[lane];
  float c1 = (lane < 36) ? (float)H[64 + lane] : 0.0f;
  float tot = c0 + c1;
#pragma unroll
  for (int off = 32; off; off >>= 1) tot += __shfl_xor(tot, off);
  float d = tot + 1e-9f;
  float q0 = c0 / d, q1 = c1 / d;
  float e = q0 * logf(q0 + 1e-9f) + q1 * logf(q1 + 1e-9f);
#pragma unroll
  for (int off = 32; off; off >>= 1) e += __shfl_xor(e, off);
  if (lane == 0) flags[row] = (-e >= 2.5f) ? 1.0f : 0.0f;
}

// ---------------------------------------------------------------------------
// Transpose + split: out_{h,l}[c][r] = split(in[r][c]).  in: [R,C] f32.
// ---------------------------------------------------------------------------
__global__ void k_tsplit(const float* __restrict__ in, u16* __restrict__ oh,
                         u16* __restrict__ ol, int R, int C) {
  __shared__ float t[32][33];
  const int c = threadIdx.x & 31, r8 = threadIdx.x >> 5;
  const int c0 = blockIdx.x * 32, r0 = blockIdx.y * 32;
#pragma unroll
  for (int p = 0; p < 4; ++p)
    t[r8 + p * 8][c] = in[(size_t)(r0 + r8 + p * 8) * C + c0 + c];
  __syncthreads();
#pragma unroll
  for (int p = 0; p < 4; ++p) {
    float v = t[c][r8 + p * 8];
    u16 h, l; split1(v, h, l);
    size_t o = (size_t)(c0 + r8 + p * 8) * R + r0 + c;
    oh[o] = h; ol[o] = l;
  }
}

// adjacency prep: aTf = adj^T (f32), Mf = adj*adj, Mt hi/lo = M^T; zero tr/cnt
__global__ void k_prep_adj(const float* __restrict__ adj, float* __restrict__ aTf,
                           float* __restrict__ Mf, u16* __restrict__ Mth,
                           u16* __restrict__ Mtl, float* __restrict__ tr,
                           unsigned int* __restrict__ cnt) {
  int idx = blockIdx.x * 256 + threadIdx.x;
  if (idx < 32) { tr[idx] = 0.0f; if (idx == 0) *cnt = 0u; }
  if (idx >= 512 * 512) return;
  int i = idx >> 9, j = idx & 511;
  float a = adj[idx];
  float m = a * a;
  Mf[idx] = m;
  aTf[j * 512 + i] = a;
  u16 h, l;
  split1(m, h, l); Mth[j * 512 + i] = h; Mtl[j * 512 + i] = l;
}

__global__ void k_prep_w1t(const float* __restrict__ w1, float* __restrict__ w1T) {
  int idx = blockIdx.x * 256 + threadIdx.x;
  if (idx < 512 * 128) { int n = idx >> 7, h = idx & 127; w1T[h * 512 + n] = w1[idx]; }
}

// ---------------------------------------------------------------------------
// Split-bf16 GEMM core: C[M,N] = A[M,K] @ B^T, B as [N,K] hi/lo bf16.
// 3-product Markidis on mfma_f32_16x16x32_bf16. BM=BN=128, BK=64, 4 waves.
// EMIT: 0 = f32 C (optional per-row flags scale), 1 = split hi/lo bf16 C.
// ---------------------------------------------------------------------------
template<int EMIT>
__device__ __forceinline__ void gemm_core(
    const float* __restrict__ A, const u16* __restrict__ Bh,
    const u16* __restrict__ Bl, float* __restrict__ C, u16* __restrict__ Ch,
    u16* __restrict__ Cl, const float* __restrict__ flags, int N, int K,
    int row0, int col0) {
  __shared__ u16 lAh[128 * 64], lAl[128 * 64], lBh[128 * 64], lBl[128 * 64];
  const int tid = threadIdx.x;
  const int lane = tid & 63;
  const int w = tid >> 6;
  const int wm = (w >> 1) * 64, wn = (w & 1) * 64;

  f32x4 acc[4][4] = {};

  const int rr = lane & 15;
  const int kgrp = (lane >> 4) * 8;
  const int sw = (rr & 7) << 3;
  const int bsrc = (((lane & 7) ^ (lane >> 3)) << 3);
  const int brow = lane >> 3;

  const int nk = K >> 6;
  for (int kt = 0; kt < nk; ++kt) {
    const int k0 = kt << 6;
    {
      const int rbase = w * 32;
#pragma unroll
      for (int i = 0; i < 4; ++i) {
        const size_t gro = (size_t)(col0 + rbase + i * 8 + brow) * K + k0 + bsrc;
        GLDS16(Bh + gro, &lBh[(rbase + i * 8) * 64]);
        GLDS16(Bl + gro, &lBl[(rbase + i * 8) * 64]);
      }
    }
    float4 av[8];
#pragma unroll
    for (int j = 0; j < 8; ++j) {
      int idx = j * 256 + tid;
      int r = idx >> 4, kv = (idx & 15) * 4;
      av[j] = *(const float4*)(A + (size_t)(row0 + r) * K + k0 + kv);
    }
#pragma unroll
    for (int j = 0; j < 8; ++j) {
      int idx = j * 256 + tid;
      int r = idx >> 4, kv = (idx & 15) * 4;
      int col = kv ^ ((r & 7) << 3);
      u16 h0, h1, h2, h3, l0, l1, l2, l3;
      split1(av[j].x, h0, l0); split1(av[j].y, h1, l1);
      split1(av[j].z, h2, l2); split1(av[j].w, h3, l3);
      *(u16x4*)&lAh[r * 64 + col] = u16x4{h0, h1, h2, h3};
      *(u16x4*)&lAl[r * 64 + col] = u16x4{l0, l1, l2, l3};
    }
    __syncthreads();
#pragma unroll
    for (int kk = 0; kk < 2; ++kk) {
      const int kx = (kk * 32 + kgrp) ^ sw;
      s16x8 ah[4], al[4], bh[4], bl[4];
#pragma unroll
      for (int mi = 0; mi < 4; ++mi) {
        const int r = (wm + mi * 16 + rr) * 64 + kx;
        ah[mi] = *(const s16x8*)&lAh[r];
        al[mi] = *(const s16x8*)&lAl[r];
      }
#pragma unroll
      for (int ni = 0; ni < 4; ++ni) {
        const int r = (wn + ni * 16 + rr) * 64 + kx;
        bh[ni] = *(const s16x8*)&lBh[r];
        bl[ni] = *(const s16x8*)&lBl[r];
      }
#pragma unroll
      for (int mi = 0; mi < 4; ++mi)
#pragma unroll
        for (int ni = 0; ni < 4; ++ni) {
          acc[mi][ni] = __builtin_amdgcn_mfma_f32_16x16x32_bf16(ah[mi], bh[ni], acc[mi][ni], 0, 0, 0);
          acc[mi][ni] = __builtin_amdgcn_mfma_f32_16x16x32_bf16(ah[mi], bl[ni], acc[mi][ni], 0, 0, 0);
          acc[mi][ni] = __builtin_amdgcn_mfma_f32_16x16x32_bf16(al[mi], bh[ni], acc[mi][ni], 0, 0, 0);
        }
    }
    __syncthreads();
  }
  const int cr = (lane >> 4) * 4;
  const int cc = lane & 15;
#pragma unroll
  for (int mi = 0; mi < 4; ++mi)
#pragma unroll
    for (int j = 0; j < 4; ++j) {
      const int grow = row0 + wm + mi * 16 + cr + j;
      const float f = (EMIT == 0 && flags) ? flags[grow] : 1.0f;
#pragma unroll
      for (int ni = 0; ni < 4; ++ni) {
        const size_t o = (size_t)grow * N + col0 + wn + ni * 16 + cc;
        if (EMIT == 0) {
          C[o] = acc[mi][ni][j] * f;
        } else {
          u16 h, l; split1(acc[mi][ni][j], h, l);
          Ch[o] = h; Cl[o] = l;
        }
      }
    }
}

template<int EMIT>
__global__ __launch_bounds__(256, 2) void k_gemm(
    const float* __restrict__ A, const u16* __restrict__ Bh,
    const u16* __restrict__ Bl, float* __restrict__ C, u16* __restrict__ Ch,
    u16* __restrict__ Cl, const float* __restrict__ flags, int N, int K) {
  gemm_core<EMIT>(A, Bh, Bl, C, Ch, Cl, flags, N, K, blockIdx.y * 128, blockIdx.x * 128);
}

// big GEMM with bijective XCD swizzle (512 blocks, 512 % 8 == 0, q = 64)
__global__ __launch_bounds__(256, 2) void k_gemm_big(
    const float* __restrict__ A, const u16* __restrict__ Bh,
    const u16* __restrict__ Bl, float* __restrict__ C,
    const float* __restrict__ flags, int N, int K) {
  int d = blockIdx.y * gridDim.x + blockIdx.x;
  int wg = (d & 7) * 64 + (d >> 3);
  gemm_core<0>(A, Bh, Bl, C, nullptr, nullptr, flags, N, K,
               (wg >> 2) * 128, (wg & 3) * 128);
}

// z=0: M3 = M2 @ M (B = M^T);  z=1: M4 = M2 @ M2 (B = M2^T)
__global__ __launch_bounds__(256, 2) void k_gemm_pow(
    const float* __restrict__ M2, const u16* __restrict__ Mth,
    const u16* __restrict__ Mtl, const u16* __restrict__ M2th,
    const u16* __restrict__ M2tl, float* __restrict__ M3, float* __restrict__ M4) {
  const u16* bh = blockIdx.z ? M2th : Mth;
  const u16* bl = blockIdx.z ? M2tl : Mtl;
  float* c = blockIdx.z ? M4 : M3;
  gemm_core<0>(M2, bh, bl, c, nullptr, nullptr, nullptr, 512, 512,
               blockIdx.y * 128, blockIdx.x * 128);
}

// ---------------------------------------------------------------------------
// Fused traces: tr1=diag(M); trk=<M^a,(M^b)^T> for k=2..8; last block finalizes
// h = sum trk/k! and writes the scalar output.
// ---------------------------------------------------------------------------
__global__ __launch_bounds__(256) void k_traces(
    const float* __restrict__ Mf, const float* __restrict__ M2,
    const float* __restrict__ M3, const float* __restrict__ M4,
    float* __restrict__ tr, unsigned int* __restrict__ cnt,
    float* __restrict__ outh, int nblocks) {
  float p[8] = {0.f, 0.f, 0.f, 0.f, 0.f, 0.f, 0.f, 0.f};
  const int idx = blockIdx.x * 256 + threadIdx.x;
  const int stride = nblocks * 256;
  for (int t = idx; t < 512 * 512; t += stride) {
    int i = t >> 9, j = t & 511;
    int tt = (j << 9) + i;
    float a0 = Mf[t], a2 = M2[t], a3 = M3[t], a4 = M4[t];
    float b0 = Mf[tt], b2 = M2[tt], b3 = M3[tt], b4 = M4[tt];
    if (i == j) p[0] += a0;
    p[1] += a0 * b0; p[2] += a0 * b2; p[3] += a2 * b2; p[4] += a2 * b3;
    p[5] += a3 * b3; p[6] += a3 * b4; p[7] += a4 * b4;
  }
  const int lane = threadIdx.x & 63, w = threadIdx.x >> 6;
#pragma unroll
  for (int k = 0; k < 8; ++k)
#pragma unroll
    for (int off = 32; off; off >>= 1) p[k] += __shfl_xor(p[k], off);
  __shared__ float red[4][8];
  if (lane == 0)
#pragma unroll
    for (int k = 0; k < 8; ++k) red[w][k] = p[k];
  __syncthreads();
  if (threadIdx.x < 8) {
    float s = red[0][threadIdx.x] + red[1][threadIdx.x] +
              red[2][threadIdx.x] + red[3][threadIdx.x];
    atomicAdd(&tr[threadIdx.x], s);
  }
  __threadfence();
  __syncthreads();
  if (threadIdx.x == 0) {
    unsigned int done = atomicAdd(cnt, 1u);
    if (done == (unsigned int)(nblocks - 1)) {
      double h = 0.0, f = 1.0;
      for (int k = 1; k <= 8; ++k) {
        f *= k;
        float tk = atomicAdd(&tr[k - 1], 0.0f);  // coherent read
        h += (double)tk / f;
      }
      outh[0] = (float)h;
    }
  }
}

// ---------------------------------------------------------------------------
// Fused robust policy (unchanged from round 1; verified correct)
// ---------------------------------------------------------------------------
__global__ __launch_bounds__(256, 2) void k_policy(
    const float* __restrict__ state, const float* __restrict__ w1,
    const float* __restrict__ w1T, const float* __restrict__ w2,
    const float* __restrict__ b1, const float* __restrict__ b2,
    float* __restrict__ out) {
  __shared__ float s[16][513];
  __shared__ float q[16][130];
  __shared__ float Rp[16][130];
  __shared__ float lg[16][66];
  __shared__ float csum[128];
  const int tid = threadIdx.x;
  const int r0 = blockIdx.x * 16;

#pragma unroll
  for (int j = 0; j < 8; ++j) {
    int idx = j * 256 + tid;
    int r = idx >> 7, c4 = (idx & 127) * 4;
    float4 v = *(const float4*)(state + (size_t)(r0 + r) * 512 + c4);
    s[r][c4 + 0] = v.x; s[r][c4 + 1] = v.y; s[r][c4 + 2] = v.z; s[r][c4 + 3] = v.w;
  }
  if (tid < 128) {
    float a = 0.f;
    const float4* wp = (const float4*)(w2 + tid * 64);
#pragma unroll
    for (int i = 0; i < 16; ++i) { float4 v = wp[i]; a += v.x + v.y + v.z + v.w; }
    csum[tid] = a;
  }
  __syncthreads();

  {
    const int h4 = (tid & 31) * 4;
    const int rg = (tid >> 5) * 2;
    float z00 = 0, z01 = 0, z02 = 0, z03 = 0, z10 = 0, z11 = 0, z12 = 0, z13 = 0;
#pragma unroll 4
    for (int n = 0; n < 512; ++n) {
      float4 wv = *(const float4*)(w1 + (size_t)n * 128 + h4);
      float s0 = s[rg][n], s1 = s[rg + 1][n];
      z00 += s0 * wv.x; z01 += s0 * wv.y; z02 += s0 * wv.z; z03 += s0 * wv.w;
      z10 += s1 * wv.x; z11 += s1 * wv.y; z12 += s1 * wv.z; z13 += s1 * wv.w;
    }
    float4 bb = *(const float4*)(b1 + h4);
    q[rg][h4 + 0] = (z00 + bb.x > 0.f) ? csum[h4 + 0] : 0.f;
    q[rg][h4 + 1] = (z01 + bb.y > 0.f) ? csum[h4 + 1] : 0.f;
    q[rg][h4 + 2] = (z02 + bb.z > 0.f) ? csum[h4 + 2] : 0.f;
    q[rg][h4 + 3] = (z03 + bb.w > 0.f) ? csum[h4 + 3] : 0.f;
    q[rg + 1][h4 + 0] = (z10 + bb.x > 0.f) ? csum[h4 + 0] : 0.f;
    q[rg + 1][h4 + 1] = (z11 + bb.y > 0.f) ? csum[h4 + 1] : 0.f;
    q[rg + 1][h4 + 2] = (z12 + bb.z > 0.f) ? csum[h4 + 2] : 0.f;
    q[rg + 1][h4 + 3] = (z13 + bb.w > 0.f) ? csum[h4 + 3] : 0.f;
  }
  __syncthreads();

  {
    const int n4 = (tid & 127) * 4;
    const int rg = (tid >> 7) * 8;
    float g[8][4] = {};
#pragma unroll 2
    for (int h = 0; h < 128; ++h) {
      float4 wv = *(const float4*)(w1T + (size_t)h * 512 + n4);
#pragma unroll
      for (int i = 0; i < 8; ++i) {
        float qq = q[rg + i][h];
        g[i][0] += qq * wv.x; g[i][1] += qq * wv.y;
        g[i][2] += qq * wv.z; g[i][3] += qq * wv.w;
      }
    }
#pragma unroll
    for (int i = 0; i < 8; ++i)
#pragma unroll
      for (int c = 0; c < 4; ++c) {
        float gg = g[i][c];
        float sgn = (gg > 0.f) ? 1.f : ((gg < 0.f) ? -1.f : 0.f);
        s[rg + i][n4 + c] -= 0.1f * sgn;
      }
  }
  __syncthreads();

  {
    const int h4 = (tid & 31) * 4;
    const int rg = (tid >> 5) * 2;
    float z00 = 0, z01 = 0, z02 = 0, z03 = 0, z10 = 0, z11 = 0, z12 = 0, z13 = 0;
#pragma unroll 4
    for (int n = 0; n < 512; ++n) {
      float4 wv = *(const float4*)(w1 + (size_t)n * 128 + h4);
      float s0 = s[rg][n], s1 = s[rg + 1][n];
      z00 += s0 * wv.x; z01 += s0 * wv.y; z02 += s0 * wv.z; z03 += s0 * wv.w;
      z10 += s1 * wv.x; z11 += s1 * wv.y; z12 += s1 * wv.z; z13 += s1 * wv.w;
    }
    float4 bb = *(const float4*)(b1 + h4);
    Rp[rg][h4 + 0] = fmaxf(z00 + bb.x, 0.f);
    Rp[rg][h4 + 1] = fmaxf(z01 + bb.y, 0.f);
    Rp[rg][h4 + 2] = fmaxf(z02 + bb.z, 0.f);
    Rp[rg][h4 + 3] = fmaxf(z03 + bb.w, 0.f);
    Rp[rg + 1][h4 + 0] = fmaxf(z10 + bb.x, 0.f);
    Rp[rg + 1][h4 + 1] = fmaxf(z11 + bb.y, 0.f);
    Rp[rg + 1][h4 + 2] = fmaxf(z12 + bb.z, 0.f);
    Rp[rg + 1][h4 + 3] = fmaxf(z13 + bb.w, 0.f);
  }
  __syncthreads();

  {
    const int a4 = (tid & 15) * 4;
    const int r = tid >> 4;
    float L0 = 0, L1 = 0, L2 = 0, L3 = 0;
#pragma unroll 4
    for (int h = 0; h < 128; ++h) {
      float rp = Rp[r][h];
      float4 wv = *(const float4*)(w2 + (size_t)h * 64 + a4);
      L0 += rp * wv.x; L1 += rp * wv.y; L2 += rp * wv.z; L3 += rp * wv.w;
    }
    float4 bb = *(const float4*)(b2 + a4);
    lg[r][a4 + 0] = L0 + bb.x; lg[r][a4 + 1] = L1 + bb.y;
    lg[r][a4 + 2] = L2 + bb.z; lg[r][a4 + 3] = L3 + bb.w;
  }
  __syncthreads();

  if (tid < 16) {
    float mx = -3.0e38f;
    for (int a = 0; a < 64; ++a) mx = fmaxf(mx, lg[tid][a]);
    float sum = 0.f;
    for (int a = 0; a < 64; ++a) { float e = __expf(lg[tid][a] - mx); lg[tid][a] = e; sum += e; }
    float inv = 1.f / sum;
    for (int a = 0; a < 64; ++a) lg[tid][a] *= inv;
  }
  __syncthreads();
#pragma unroll
  for (int j = 0; j < 4; ++j) {
    int idx = j * 256 + tid;
    int r = idx >> 6, a = idx & 63;
    out[(size_t)(r0 + r) * 64 + a] = lg[r][a];
  }
}

// ---------------------------------------------------------------------------
extern "C" void kernel_launch(void* const* d_in, const int* in_sizes, int n_in,
                              void* d_out, int out_size, void* d_ws, size_t ws_size,
                              hipStream_t stream) {
  const float* E   = (const float*)d_in[0];   // [16384,5120]
  const float* S   = (const float*)d_in[1];   // [512,5120]
  const float* adj = (const float*)d_in[2];   // [512,512]
  const float* w1  = (const float*)d_in[3];   // [512,128]
  const float* b1  = (const float*)d_in[4];   // [128]
  const float* w2  = (const float*)d_in[5];   // [128,64]
  const float* b2  = (const float*)d_in[6];   // [64]
  float* out = (float*)d_out;                 // [16384*64] probs + [1] h_acyclic

  char* wsb = (char*)d_ws;
  size_t off = 0;
  auto alloc = [&](size_t bytes) { void* p = wsb + off; off += (bytes + 255) & ~(size_t)255; return p; };
  u16*   STh  = (u16*)alloc((size_t)5120 * 512 * 2);
  u16*   STl  = (u16*)alloc((size_t)5120 * 512 * 2);
  u16*   WTh  = (u16*)alloc((size_t)512 * 5120 * 2);
  u16*   WTl  = (u16*)alloc((size_t)512 * 5120 * 2);
  float* st   = (float*)alloc((size_t)16384 * 512 * 4);
  float* w1T  = (float*)alloc((size_t)128 * 512 * 4);
  float* flg  = (float*)alloc((size_t)16384 * 4);
  float* aTf  = (float*)alloc((size_t)512 * 512 * 4);
  float* Mf   = (float*)alloc((size_t)512 * 512 * 4);
  u16*   Mth  = (u16*)alloc((size_t)512 * 512 * 2);
  u16*   Mtl  = (u16*)alloc((size_t)512 * 512 * 2);
  float* M2   = (float*)alloc((size_t)512 * 512 * 4);
  float* M3   = (float*)alloc((size_t)512 * 512 * 4);
  float* M4   = (float*)alloc((size_t)512 * 512 * 4);
  u16*   M2th = (u16*)alloc((size_t)512 * 512 * 2);
  u16*   M2tl = (u16*)alloc((size_t)512 * 512 * 2);
  float* tr   = (float*)alloc(128);
  unsigned int* cnt = (unsigned int*)alloc(128);
  (void)in_sizes; (void)n_in; (void)out_size; (void)ws_size;

  // prep chain for W^T = (S^T @ adj)^T, emitted directly as split bf16
  k_prep_adj<<<1024, 256, 0, stream>>>(adj, aTf, Mf, Mth, Mtl, tr, cnt);
  k_prep_w1t<<<256, 256, 0, stream>>>(w1, w1T);
  k_tsplit<<<dim3(160, 16), 256, 0, stream>>>(S, STh, STl, 512, 5120);
  k_gemm<1><<<dim3(40, 4), 256, 0, stream>>>(aTf, STh, STl, nullptr, WTh, WTl,
                                             nullptr, 5120, 512);
  // entropy flags
  k_hist<<<4096, 256, 0, stream>>>(E, flg);
  // state = flags ⊙ (E @ W) — the single big GEMM (fused former GEMM1+GEMM2)
  k_gemm_big<<<dim3(4, 128), 256, 0, stream>>>(E, WTh, WTl, st, flg, 512, 5120);
  // NOTEARS powers + traces
  k_gemm<0><<<dim3(4, 4), 256, 0, stream>>>(Mf, Mth, Mtl, M2, nullptr, nullptr,
                                            nullptr, 512, 512);
  k_tsplit<<<dim3(16, 16), 256, 0, stream>>>(M2, M2th, M2tl, 512, 512);
  k_gemm_pow<<<dim3(4, 4, 2), 256, 0, stream>>>(M2, Mth, Mtl, M2th, M2tl, M3, M4);
  k_traces<<<120, 256, 0, stream>>>(Mf, M2, M3, M4, tr, cnt,
                                    out + (size_t)16384 * 64, 120);
  // policy
  k_policy<<<1024, 256, 0, stream>>>(st, w1, w1T, w2, b1, b2, out);
}